// Round 4
// baseline (21.442 us; speedup 1.0000x reference)
//
#include <hip/hip_runtime.h>

// EctTransform: out[b,r,t] = (sum_n sigmoid(100*(lin_r - x[b,n,:].v[:,t]))) / max_{r,t}
// B=16, N=2048, D=3, R=64, T=64.
//
// Round 15: occupancy experiment. r13/r14 established e2e == kernel time
// (+~0.7us), so the two kernels really sum to ~18us while the instruction
// floor is ~3-6us -> the partial kernel is STALL-dominated, not issue-bound.
// r12 ran 2 blocks/CU = 4 waves/SIMD; the inner loop's dep chains
// (dot->min->exp->mul->t->d->merge->rcp->fma) span both VALU and trans
// pipes and 4 waves may not cover the latency. This round: r11 geometry
// (NSPLIT=8, BPTS=256, WPTS=32 -> 1024 blocks) with the launch bound r11
// got wrong: __launch_bounds__(512, 8) -> 8 waves/SIMD -> 4 blocks/CU
// resident -> 1024 blocks in ONE round at 32 waves/CU (100% occupancy).
// VGPR 48 <= 64 cap, LDS 19KB x 4 = 76KB <= 160KB. Math bit-identical to
// r11/r12 (clamp m<=48; g0=min(u,2^30); g1=u*c^4; packed pair-merge).
// Norm back to NSPLIT=8 (2MB read, ~+0.3us) - the price of the experiment.
// If flat vs r12 -> kernel is issue-bound at 4 waves; formulation roofline.
// Grid: 16b x 8rg x 8s = 1024 blocks x 512 thr (8 waves x 32 pts).

#define BATCH  16
#define NPTS   2048
#define RES    64
#define NT     64
#define RPER   8
#define NSPLIT 8
#define NWAVES 8
#define WPTS   32                       // points per wave
#define BPTS   256                      // points per block
#define HPTS   128                      // even/odd halves per block
#define CLAMP30 1073741824.0f           // 2^30

typedef float v2f __attribute__((ext_vector_type(2)));

__device__ __forceinline__ float fexp2(float x) { return __builtin_amdgcn_exp2f(x); }
__device__ __forceinline__ float frcp(float x)  { return __builtin_amdgcn_rcpf(x); }
__device__ __forceinline__ v2f fma2(v2f a, v2f b, v2f c) { return __builtin_elementwise_fma(a, b, c); }
__device__ __forceinline__ v2f min2(v2f a, v2f b) { return __builtin_elementwise_min(a, b); }

__global__ __launch_bounds__(512, 8)
void ect_partial_kernel(const float* __restrict__ x, const float* __restrict__ v,
                        float* __restrict__ part) {
    const int tid  = threadIdx.x;
    const int lane = tid & 63;          // t
    const int w    = tid >> 6;          // wave (8 per block)
    const int bid  = blockIdx.x;
    const int s    = bid & 7;           // n-chunk of 256
    const int rg   = (bid >> 3) & 7;    // r-group of 8
    const int b    = bid >> 6;

    __shared__ float xe[HPTS], ye[HPTS], ze[HPTS];   // even points (SoA)
    __shared__ float xo[HPTS], yo[HPTS], zo[HPTS];   // odd points
    __shared__ float red[NWAVES][RPER * 64];         // 16 KB

    if (tid < BPTS) {
        const float* xb = x + ((size_t)b * NPTS + (size_t)s * BPTS + tid) * 3;
        const float x0 = xb[0], y0 = xb[1], z0 = xb[2];
        const int h = tid >> 1;
        if (tid & 1) { xo[h] = x0; yo[h] = y0; zo[h] = z0; }
        else         { xe[h] = x0; ye[h] = y0; ze[h] = z0; }
    }

    const float K    = 144.26950408889634f;   // 100 * log2(e)
    const float step = 2.0f / 63.0f;
    const float Ks   = K * step;              // 4.58 per r-step

    const float msv0 = K * v[0 * NT + lane];
    const float msv1 = K * v[1 * NT + lane];
    const float msv2 = K * v[2 * NT + lane];
    const float mslin = -K * (-1.0f + step * (float)(rg * RPER));
    const v2f msv0v = {msv0, msv0}, msv1v = {msv1, msv1}, msv2v = {msv2, msv2};
    const v2f mslinv = {mslin, mslin};

    const float c1 = fexp2(-Ks);
    const float c2 = c1 * c1, c3 = c2 * c1, c4 = c3 * c1, c6 = c4 * c2;
    const v2f Cv[4]  = {{1.0f, 1.0f}, {c1, c1}, {c2, c2}, {c3, c3}};
    const v2f C2v[4] = {{1.0f, 1.0f}, {c2, c2}, {c4, c4}, {c6, c6}};
    const v2f ONE = {1.0f, 1.0f};
    const v2f CL30 = {CLAMP30, CLAMP30};
    const v2f C4v  = {c4, c4};
    const v2f M48  = {48.0f, 48.0f};

    __syncthreads();

    v2f acc[2][4];
#pragma unroll
    for (int g = 0; g < 2; ++g)
#pragma unroll
        for (int j = 0; j < 4; ++j) acc[g][j] = (v2f){0.0f, 0.0f};

#pragma unroll
    for (int it = 0; it < WPTS / 8; ++it) {
        const int base = w * (WPTS / 2) + it * 4;     // pair index, wave-uniform
        const v2f xe0 = *(const v2f*)&xe[base],  xe1 = *(const v2f*)&xe[base + 2];
        const v2f ye0 = *(const v2f*)&ye[base],  ye1 = *(const v2f*)&ye[base + 2];
        const v2f ze0 = *(const v2f*)&ze[base],  ze1 = *(const v2f*)&ze[base + 2];
        const v2f xo0 = *(const v2f*)&xo[base],  xo1 = *(const v2f*)&xo[base + 2];
        const v2f yo0 = *(const v2f*)&yo[base],  yo1 = *(const v2f*)&yo[base + 2];
        const v2f zo0 = *(const v2f*)&zo[base],  zo1 = *(const v2f*)&zo[base + 2];

        // dots (packed, 2 points per instr), clamp m<=48
        v2f mE0 = fma2(ze0, msv2v, fma2(ye0, msv1v, fma2(xe0, msv0v, mslinv)));
        v2f mE1 = fma2(ze1, msv2v, fma2(ye1, msv1v, fma2(xe1, msv0v, mslinv)));
        v2f mO0 = fma2(zo0, msv2v, fma2(yo0, msv1v, fma2(xo0, msv0v, mslinv)));
        v2f mO1 = fma2(zo1, msv2v, fma2(yo1, msv1v, fma2(xo1, msv0v, mslinv)));
        mE0 = min2(mE0, M48); mE1 = min2(mE1, M48);
        mO0 = min2(mO0, M48); mO1 = min2(mO1, M48);

        v2f uE0, uE1, uO0, uO1;
        uE0.x = fexp2(mE0.x); uE0.y = fexp2(mE0.y);
        uE1.x = fexp2(mE1.x); uE1.y = fexp2(mE1.y);
        uO0.x = fexp2(mO0.x); uO0.y = fexp2(mO0.y);
        uO1.x = fexp2(mO1.x); uO1.y = fexp2(mO1.y);

        // group bases: g0 clamped to 2^30; g1 = u*c^4 (<= 2^29.7, clamp-free)
        const v2f g0E0 = min2(uE0, CL30), g0E1 = min2(uE1, CL30);
        const v2f g0O0 = min2(uO0, CL30), g0O1 = min2(uO1, CL30);
        const v2f g1E0 = uE0 * C4v, g1E1 = uE1 * C4v;
        const v2f g1O0 = uO0 * C4v, g1O1 = uO1 * C4v;

        // packed pair sums/products: lanes = pairs (p0,p1),(p2,p3) / (p4,p5),(p6,p7)
        const v2f S[2][2] = {{g0E0 + g0O0, g0E1 + g0O1}, {g1E0 + g1O0, g1E1 + g1O1}};
        const v2f P[2][2] = {{g0E0 * g0O0, g0E1 * g0O1}, {g1E0 * g1O0, g1E1 * g1O1}};

#pragma unroll
        for (int g = 0; g < 2; ++g) {
#pragma unroll
            for (int j = 0; j < 4; ++j) {
                const v2f tA = fma2(S[g][0], Cv[j], ONE);
                const v2f dA = fma2(P[g][0], C2v[j], tA);
                const v2f tB = fma2(S[g][1], Cv[j], ONE);
                const v2f dB = fma2(P[g][1], C2v[j], tB);
                const v2f ds = dA + dB;
                const v2f num = fma2(tA, dB, fma2(tB, dA, ds));
                const v2f den = dA * dB;
                v2f R; R.x = frcp(den.x); R.y = frcp(den.y);
                acc[g][j] = fma2(num, R, acc[g][j]);
            }
        }
    }

    // block reduce over the 8 waves -> partial [8r][64t]
#pragma unroll
    for (int g = 0; g < 2; ++g)
#pragma unroll
        for (int j = 0; j < 4; ++j)
            red[w][(g * 4 + j) * 64 + lane] = acc[g][j].x + acc[g][j].y;
    __syncthreads();

    {   // all 512 threads: one output cell each
        float sum = 0.0f;
#pragma unroll
        for (int q = 0; q < NWAVES; ++q) sum += red[q][tid];
        part[((size_t)(b * NSPLIT + s)) * (RES * NT) + rg * 512 + tid] = sum;
    }
}

__global__ __launch_bounds__(1024, 2)
void ect_norm_kernel(const float* __restrict__ part, float* __restrict__ out) {
    const int b   = blockIdx.x;
    const int tid = threadIdx.x;               // one float4 cell per thread (1024 cells)

    const float4* pb = (const float4*)(part + (size_t)b * NSPLIT * (RES * NT));
    float4 s4 = pb[tid];
#pragma unroll
    for (int c = 1; c < NSPLIT; ++c) {
        const float4 q4 = pb[c * 1024 + tid];
        s4.x += q4.x; s4.y += q4.y; s4.z += q4.z; s4.w += q4.w;
    }

    float m = fmaxf(fmaxf(s4.x, s4.y), fmaxf(s4.z, s4.w));
#pragma unroll
    for (int off = 32; off >= 1; off >>= 1)
        m = fmaxf(m, __shfl_xor(m, off, 64));

    __shared__ float sm[16];
    if ((tid & 63) == 0) sm[tid >> 6] = m;
    __syncthreads();
    float g = sm[0];
#pragma unroll
    for (int i = 1; i < 16; ++i) g = fmaxf(g, sm[i]);

    const float rinv = frcp(g);
    float4 o;
    o.x = s4.x * rinv; o.y = s4.y * rinv; o.z = s4.z * rinv; o.w = s4.w * rinv;
    ((float4*)(out + (size_t)b * (RES * NT)))[tid] = o;
}

extern "C" void kernel_launch(void* const* d_in, const int* in_sizes, int n_in,
                              void* d_out, int out_size, void* d_ws, size_t ws_size,
                              hipStream_t stream) {
    const float* x = (const float*)d_in[0];   // (16, 2048, 3)
    const float* v = (const float*)d_in[1];   // (3, 64)
    float* out  = (float*)d_out;              // (16, 64, 64)
    float* part = (float*)d_ws;               // [16][8][4096] f32 = 2 MB

    ect_partial_kernel<<<BATCH * RPER * NSPLIT, 512, 0, stream>>>(x, v, part);
    ect_norm_kernel<<<BATCH, 1024, 0, stream>>>(part, out);
}

// Round 5
// 18.680 us; speedup vs baseline: 1.1479x; 1.1479x over previous
//
#include <hip/hip_runtime.h>

// EctTransform: out[b,r,t] = (sum_n sigmoid(100*(lin_r - x[b,n,:].v[:,t]))) / max_{r,t}
// B=16, N=2048, D=3, R=64, T=64.
//
// Round 16: r12 config exactly (512 blocks x 512 thr, 2 blocks/CU, WPTS=64,
// bit-identical math: clamp m<=48; g0=min(u,2^30); g1=u*c^4; packed
// pair-merge 4-way fractions), ONE change: main loop unroll 8 -> 2.
// Rationale: r12/r11/r15 geometry triangulation gives per-block fixed cost
// ~1.2us (2900 cyc). Full unroll makes the body ~14KB of straight-line
// code; each CU cold-walks ~220 L1I lines once per launch (2 blocks/CU =
// no warm reuse). unroll 2 cuts I$ footprint 4x (~3.5KB) at ~1% issue
// overhead; 2-iter body still has 16 independent fraction blocks of ILP.
// Occupancy was falsified as the lever in r15 (more waves = slower).
// Grid: 16b x 8rg x 4s = 512 blocks x 512 thr (8 waves x 64 pts) = 2/CU.

#define BATCH  16
#define NPTS   2048
#define RES    64
#define NT     64
#define RPER   8
#define NSPLIT 4
#define NWAVES 8
#define WPTS   64                       // points per wave
#define BPTS   512                      // points per block
#define HPTS   256                      // even/odd halves per block
#define CLAMP30 1073741824.0f           // 2^30

typedef float v2f __attribute__((ext_vector_type(2)));

__device__ __forceinline__ float fexp2(float x) { return __builtin_amdgcn_exp2f(x); }
__device__ __forceinline__ float frcp(float x)  { return __builtin_amdgcn_rcpf(x); }
__device__ __forceinline__ v2f fma2(v2f a, v2f b, v2f c) { return __builtin_elementwise_fma(a, b, c); }
__device__ __forceinline__ v2f min2(v2f a, v2f b) { return __builtin_elementwise_min(a, b); }

__global__ __launch_bounds__(512, 4)
void ect_partial_kernel(const float* __restrict__ x, const float* __restrict__ v,
                        float* __restrict__ part) {
    const int tid  = threadIdx.x;
    const int lane = tid & 63;          // t
    const int w    = tid >> 6;          // wave (8 per block)
    const int bid  = blockIdx.x;
    const int s    = bid & 3;           // n-chunk of 512
    const int rg   = (bid >> 2) & 7;    // r-group of 8
    const int b    = bid >> 5;

    __shared__ float xe[HPTS], ye[HPTS], ze[HPTS];   // even points (SoA)
    __shared__ float xo[HPTS], yo[HPTS], zo[HPTS];   // odd points
    __shared__ float red[NWAVES][RPER * 64];         // 16 KB

    {   // all 512 threads stage one point each
        const float* xb = x + ((size_t)b * NPTS + (size_t)s * BPTS + tid) * 3;
        const float x0 = xb[0], y0 = xb[1], z0 = xb[2];
        const int h = tid >> 1;
        if (tid & 1) { xo[h] = x0; yo[h] = y0; zo[h] = z0; }
        else         { xe[h] = x0; ye[h] = y0; ze[h] = z0; }
    }

    const float K    = 144.26950408889634f;   // 100 * log2(e)
    const float step = 2.0f / 63.0f;
    const float Ks   = K * step;              // 4.58 per r-step

    const float msv0 = K * v[0 * NT + lane];
    const float msv1 = K * v[1 * NT + lane];
    const float msv2 = K * v[2 * NT + lane];
    const float mslin = -K * (-1.0f + step * (float)(rg * RPER));
    const v2f msv0v = {msv0, msv0}, msv1v = {msv1, msv1}, msv2v = {msv2, msv2};
    const v2f mslinv = {mslin, mslin};

    const float c1 = fexp2(-Ks);
    const float c2 = c1 * c1, c3 = c2 * c1, c4 = c3 * c1, c6 = c4 * c2;
    const v2f Cv[4]  = {{1.0f, 1.0f}, {c1, c1}, {c2, c2}, {c3, c3}};
    const v2f C2v[4] = {{1.0f, 1.0f}, {c2, c2}, {c4, c4}, {c6, c6}};
    const v2f ONE = {1.0f, 1.0f};
    const v2f CL30 = {CLAMP30, CLAMP30};
    const v2f C4v  = {c4, c4};
    const v2f M48  = {48.0f, 48.0f};

    __syncthreads();

    v2f acc[2][4];
#pragma unroll
    for (int g = 0; g < 2; ++g)
#pragma unroll
        for (int j = 0; j < 4; ++j) acc[g][j] = (v2f){0.0f, 0.0f};

#pragma unroll 2
    for (int it = 0; it < WPTS / 8; ++it) {
        const int base = w * (WPTS / 2) + it * 4;     // pair index, wave-uniform
        const v2f xe0 = *(const v2f*)&xe[base],  xe1 = *(const v2f*)&xe[base + 2];
        const v2f ye0 = *(const v2f*)&ye[base],  ye1 = *(const v2f*)&ye[base + 2];
        const v2f ze0 = *(const v2f*)&ze[base],  ze1 = *(const v2f*)&ze[base + 2];
        const v2f xo0 = *(const v2f*)&xo[base],  xo1 = *(const v2f*)&xo[base + 2];
        const v2f yo0 = *(const v2f*)&yo[base],  yo1 = *(const v2f*)&yo[base + 2];
        const v2f zo0 = *(const v2f*)&zo[base],  zo1 = *(const v2f*)&zo[base + 2];

        // dots (packed, 2 points per instr), clamp m<=48
        v2f mE0 = fma2(ze0, msv2v, fma2(ye0, msv1v, fma2(xe0, msv0v, mslinv)));
        v2f mE1 = fma2(ze1, msv2v, fma2(ye1, msv1v, fma2(xe1, msv0v, mslinv)));
        v2f mO0 = fma2(zo0, msv2v, fma2(yo0, msv1v, fma2(xo0, msv0v, mslinv)));
        v2f mO1 = fma2(zo1, msv2v, fma2(yo1, msv1v, fma2(xo1, msv0v, mslinv)));
        mE0 = min2(mE0, M48); mE1 = min2(mE1, M48);
        mO0 = min2(mO0, M48); mO1 = min2(mO1, M48);

        v2f uE0, uE1, uO0, uO1;
        uE0.x = fexp2(mE0.x); uE0.y = fexp2(mE0.y);
        uE1.x = fexp2(mE1.x); uE1.y = fexp2(mE1.y);
        uO0.x = fexp2(mO0.x); uO0.y = fexp2(mO0.y);
        uO1.x = fexp2(mO1.x); uO1.y = fexp2(mO1.y);

        // group bases: g0 clamped to 2^30; g1 = u*c^4 (<= 2^29.7, clamp-free)
        const v2f g0E0 = min2(uE0, CL30), g0E1 = min2(uE1, CL30);
        const v2f g0O0 = min2(uO0, CL30), g0O1 = min2(uO1, CL30);
        const v2f g1E0 = uE0 * C4v, g1E1 = uE1 * C4v;
        const v2f g1O0 = uO0 * C4v, g1O1 = uO1 * C4v;

        // packed pair sums/products: lanes = pairs (p0,p1),(p2,p3) / (p4,p5),(p6,p7)
        const v2f S[2][2] = {{g0E0 + g0O0, g0E1 + g0O1}, {g1E0 + g1O0, g1E1 + g1O1}};
        const v2f P[2][2] = {{g0E0 * g0O0, g0E1 * g0O1}, {g1E0 * g1O0, g1E1 * g1O1}};

#pragma unroll
        for (int g = 0; g < 2; ++g) {
#pragma unroll
            for (int j = 0; j < 4; ++j) {
                const v2f tA = fma2(S[g][0], Cv[j], ONE);
                const v2f dA = fma2(P[g][0], C2v[j], tA);
                const v2f tB = fma2(S[g][1], Cv[j], ONE);
                const v2f dB = fma2(P[g][1], C2v[j], tB);
                const v2f ds = dA + dB;
                const v2f num = fma2(tA, dB, fma2(tB, dA, ds));
                const v2f den = dA * dB;
                v2f R; R.x = frcp(den.x); R.y = frcp(den.y);
                acc[g][j] = fma2(num, R, acc[g][j]);
            }
        }
    }

    // block reduce over the 8 waves -> partial [8r][64t]
#pragma unroll
    for (int g = 0; g < 2; ++g)
#pragma unroll
        for (int j = 0; j < 4; ++j)
            red[w][(g * 4 + j) * 64 + lane] = acc[g][j].x + acc[g][j].y;
    __syncthreads();

    {   // all 512 threads: one output cell each
        float sum = 0.0f;
#pragma unroll
        for (int q = 0; q < NWAVES; ++q) sum += red[q][tid];
        part[((size_t)(b * NSPLIT + s)) * (RES * NT) + rg * 512 + tid] = sum;
    }
}

__global__ __launch_bounds__(1024, 2)
void ect_norm_kernel(const float* __restrict__ part, float* __restrict__ out) {
    const int b   = blockIdx.x;
    const int tid = threadIdx.x;               // one float4 cell per thread (1024 cells)

    const float4* pb = (const float4*)(part + (size_t)b * NSPLIT * (RES * NT));
    float4 s4 = pb[tid];
#pragma unroll
    for (int c = 1; c < NSPLIT; ++c) {
        const float4 q4 = pb[c * 1024 + tid];
        s4.x += q4.x; s4.y += q4.y; s4.z += q4.z; s4.w += q4.w;
    }

    float m = fmaxf(fmaxf(s4.x, s4.y), fmaxf(s4.z, s4.w));
#pragma unroll
    for (int off = 32; off >= 1; off >>= 1)
        m = fmaxf(m, __shfl_xor(m, off, 64));

    __shared__ float sm[16];
    if ((tid & 63) == 0) sm[tid >> 6] = m;
    __syncthreads();
    float g = sm[0];
#pragma unroll
    for (int i = 1; i < 16; ++i) g = fmaxf(g, sm[i]);

    const float rinv = frcp(g);
    float4 o;
    o.x = s4.x * rinv; o.y = s4.y * rinv; o.z = s4.z * rinv; o.w = s4.w * rinv;
    ((float4*)(out + (size_t)b * (RES * NT)))[tid] = o;
}

extern "C" void kernel_launch(void* const* d_in, const int* in_sizes, int n_in,
                              void* d_out, int out_size, void* d_ws, size_t ws_size,
                              hipStream_t stream) {
    const float* x = (const float*)d_in[0];   // (16, 2048, 3)
    const float* v = (const float*)d_in[1];   // (3, 64)
    float* out  = (float*)d_out;              // (16, 64, 64)
    float* part = (float*)d_ws;               // [16][4][4096] f32 = 1 MB

    ect_partial_kernel<<<BATCH * RPER * NSPLIT, 512, 0, stream>>>(x, v, part);
    ect_norm_kernel<<<BATCH, 1024, 0, stream>>>(part, out);
}